// Round 9
// baseline (460.867 us; speedup 1.0000x reference)
//
#include <hip/hip_runtime.h>

#define NBq 16384
#define NXq 512
#define NUq 256
#define NYq 128
#define NQq 256
#define KP  1024   // P width: [x(512) | w(256) | u(256)]
#define AUGW 1536  // [E(512) | F(512) | B1(256) | B2(256)]

typedef __attribute__((ext_vector_type(8))) short short8;
typedef __attribute__((ext_vector_type(4))) float f32x4;

__device__ __forceinline__ ushort f2bf(float f) {
  uint x = __float_as_uint(f);
  x += 0x7FFFu + ((x >> 16) & 1u);   // RNE
  return (ushort)(x >> 16);
}

// async global->LDS, 16B per lane; LDS dest is wave-uniform base + lane*16
#define GLOAD_LDS16(g, l)                                             \
  __builtin_amdgcn_global_load_lds(                                   \
      (const __attribute__((address_space(1))) void*)(g),             \
      (__attribute__((address_space(3))) void*)(l), 16, 0, 0)

__device__ __forceinline__ float rdlane(float x, int l) {
  return __int_as_float(__builtin_amdgcn_readlane(__float_as_int(x), l));
}

// ---------------- fused prep: pack x,u -> P ; AUG ; Wxu ; D11B ; Wfull static rows ----------------
__global__ __launch_bounds__(256) void k_prep(const float* __restrict__ x, const float* __restrict__ u,
                                              const float* __restrict__ E, const float* __restrict__ F,
                                              const float* __restrict__ B1, const float* __restrict__ B2,
                                              const float* __restrict__ C1, const float* __restrict__ C2,
                                              const float* __restrict__ D11, const float* __restrict__ D12,
                                              const float* __restrict__ D21,
                                              ushort* __restrict__ P, float* __restrict__ AUG,
                                              ushort* __restrict__ Wxu, ushort* __restrict__ D11B,
                                              ushort* __restrict__ Wfull) {
  int b = blockIdx.x, tid = threadIdx.x;
  if (b < 12288) {                       // pack x,u (float4 -> bf16x4)
    int idx = b * 256 + tid;
    const int nx4 = NBq * NXq / 4;
    if (idx < nx4) {
      float4 v = *(const float4*)(x + (size_t)idx * 4);
      int row = idx >> 7, c4 = idx & 127;
      ushort4 h = { f2bf(v.x), f2bf(v.y), f2bf(v.z), f2bf(v.w) };
      *(ushort4*)(P + (size_t)row * KP + c4 * 4) = h;
    } else {
      int i = idx - nx4;
      float4 v = *(const float4*)(u + (size_t)i * 4);
      int row = i >> 6, c4 = i & 63;
      ushort4 h = { f2bf(v.x), f2bf(v.y), f2bf(v.z), f2bf(v.w) };
      *(ushort4*)(P + (size_t)row * KP + 768 + c4 * 4) = h;
    }
  } else if (b < 15360) {                // AUG = [E | F B1 B2]
    int idx = (b - 12288) * 256 + tid;
    int r = idx / AUGW, c = idx % AUGW;
    float v;
    if (c < 512)       v = E[r * 512 + c];
    else if (c < 1024) v = F[r * 512 + (c - 512)];
    else if (c < 1280) v = B1[r * 256 + (c - 1024)];
    else               v = B2[r * 256 + (c - 1280)];
    AUG[idx] = v;
  } else if (b < 16384) {                // Wxu = [C1 | 0 | D12] bf16
    int idx = (b - 15360) * 256 + tid;
    int r = idx >> 10, k = idx & 1023;
    float v;
    if (k < 512)      v = C1[r * 512 + k];
    else if (k < 768) v = 0.f;
    else              v = D12[r * 256 + (k - 768)];
    Wxu[idx] = f2bf(v);
  } else if (b < 16640) {                // D11 -> bf16
    int idx = (b - 16384) * 256 + tid;
    D11B[idx] = f2bf(D11[idx]);
  } else {                               // Wfull rows 512..639 = [C2 | D21 | 0]
    int idx = (b - 16640) * 256 + tid;   // < 131072
    int j = idx >> 10, k = idx & 1023;
    float v;
    if (k < 512)      v = C2[j * 512 + k];
    else if (k < 768) v = D21[j * 256 + (k - 512)];
    else              v = 0.f;
    Wfull[(size_t)(512 + j) * KP + k] = f2bf(v);
  }
}

// ---------------- solve helpers (MFMA tanh forward substitution, lane-local) ----------------
#define WSTRIDE 264
#define TANH_K 2.8853900817779268f   // 2*log2(e): exp(2v) = exp2(v*TANH_K)

struct Pre {
  f32x4 xuv;        // C-in: xu[r0w + (lane&15)][kt + 4*(lane>>4) + 0..3]
  short8 b[8];      // D11B fragments (A-operand)
  f32x4 rl2, bv2;   // per serial col 4*(lane&3)+i: TANH_K/lam, bv*TANH_K/lam
};

template<int t>
__device__ __forceinline__ void tile_loads(const float* __restrict__ xu,
                                           const ushort* __restrict__ D11B,
                                           const float* __restrict__ lam,
                                           const float* __restrict__ bv,
                                           int lane, int r0w, Pre& pre) {
  constexpr int kt = t * 16;
  constexpr int cmax = (t + 1) >> 1;
  const int mr = lane & 15, kq = lane >> 4, q = lane & 3;
  pre.xuv = *(const f32x4*)(&xu[(size_t)(r0w + mr) * NQq + kt + kq * 4]);
  #pragma unroll
  for (int c = 0; c < cmax; ++c)
    pre.b[c] = *(const short8*)(D11B + (size_t)(kt + mr) * NQq + c * 32 + kq * 8);
  float4 l4 = *(const float4*)(&lam[kt + q * 4]);
  float4 b4 = *(const float4*)(&bv[kt + q * 4]);
  pre.rl2[0] = TANH_K / l4.x; pre.rl2[1] = TANH_K / l4.y;
  pre.rl2[2] = TANH_K / l4.z; pre.rl2[3] = TANH_K / l4.w;
  pre.bv2[0] = b4.x * pre.rl2[0]; pre.bv2[1] = b4.y * pre.rl2[1];
  pre.bv2[2] = b4.z * pre.rl2[2]; pre.bv2[3] = b4.w * pre.rl2[3];
}

// one serial step: broadcast w[col k-1] within the quad, rank-1 update, tanh.
#define SOLVE_STEP(k, dvreg)                                                   \
  {                                                                            \
    float wb_ = __int_as_float(__builtin_amdgcn_update_dpp(                    \
        0, __float_as_int(wreg), (((k - 1) >> 2) * 0x55), 0xF, 0xF, true));    \
    acc[0] = fmaf(dvreg.x, wb_, acc[0]);                                       \
    acc[1] = fmaf(dvreg.y, wb_, acc[1]);                                       \
    acc[2] = fmaf(dvreg.z, wb_, acc[2]);                                       \
    acc[3] = fmaf(dvreg.w, wb_, acc[3]);                                       \
    if constexpr ((k) + 3 <= 14) dvreg = *(const float4*)(&dT[(k) + 3][q4]);   \
    float v_ = fmaf(acc[(k) & 3], rl2[(k) & 3], bv2[(k) & 3]);                 \
    float e_ = __builtin_amdgcn_exp2f(v_);                                     \
    float w_ = fmaf(-2.f, __builtin_amdgcn_rcpf(1.f + e_), 1.f);               \
    wreg = w_;                                                                 \
    if (q == ((k) >> 2)) wk[(k) & 3] = w_;                                     \
  }

template<int t>
__device__ __forceinline__ void do_tile(const float* __restrict__ xu,
                                        const ushort* __restrict__ D11B,
                                        const float* __restrict__ lam,
                                        const float* __restrict__ bv,
                                        ushort* wb, const float (*d11T)[16][16],
                                        short8 (&whiF)[8], int lane, int bp4,
                                        int r0w, Pre& cur, Pre& nxt) {
  constexpr int kt = t * 16;
  constexpr int cmax = (t + 1) >> 1;
  if constexpr (t < 15)
    tile_loads<t + 1>(xu, D11B, lam, bv, lane, r0w, nxt);
  const int q = lane & 3, r2 = lane >> 2;
  const int q4 = q * 4;
  const float (*dT)[16] = d11T[t];
  float4 dvb0 = *(const float4*)(&dT[0][q4]);
  float4 dvb1 = *(const float4*)(&dT[1][q4]);
  float4 dvb2 = *(const float4*)(&dT[2][q4]);
  float4 dvb3 = *(const float4*)(&dT[3][q4]);
  f32x4 accM = cur.xuv;
  #pragma unroll
  for (int c = 0; c < cmax; ++c)
    accM = __builtin_amdgcn_mfma_f32_16x16x32_bf16(cur.b[c], whiF[c], accM, 0, 0, 0);
  f32x4 acc;
  acc[0] = __int_as_float(__builtin_amdgcn_ds_bpermute(bp4, __float_as_int(accM[0])));
  acc[1] = __int_as_float(__builtin_amdgcn_ds_bpermute(bp4, __float_as_int(accM[1])));
  acc[2] = __int_as_float(__builtin_amdgcn_ds_bpermute(bp4, __float_as_int(accM[2])));
  acc[3] = __int_as_float(__builtin_amdgcn_ds_bpermute(bp4, __float_as_int(accM[3])));
  const f32x4 rl2 = cur.rl2, bv2 = cur.bv2;
  float wreg = 0.f, wk[4] = {0.f, 0.f, 0.f, 0.f};
  {  // step 0
    float v_ = fmaf(acc[0], rl2[0], bv2[0]);
    float e_ = __builtin_amdgcn_exp2f(v_);
    float w_ = fmaf(-2.f, __builtin_amdgcn_rcpf(1.f + e_), 1.f);
    wreg = w_;
    if (q == 0) wk[0] = w_;
  }
  SOLVE_STEP(1, dvb0)
  SOLVE_STEP(2, dvb1)
  SOLVE_STEP(3, dvb2)
  SOLVE_STEP(4, dvb3)
  SOLVE_STEP(5, dvb0)
  SOLVE_STEP(6, dvb1)
  SOLVE_STEP(7, dvb2)
  SOLVE_STEP(8, dvb3)
  SOLVE_STEP(9, dvb0)
  SOLVE_STEP(10, dvb1)
  SOLVE_STEP(11, dvb2)
  SOLVE_STEP(12, dvb3)
  SOLVE_STEP(13, dvb0)
  SOLVE_STEP(14, dvb1)
  SOLVE_STEP(15, dvb2)
  ushort4 h = { f2bf(wk[0]), f2bf(wk[1]), f2bf(wk[2]), f2bf(wk[3]) };
  *(ushort4*)(wb + r2 * WSTRIDE + kt + q * 4) = h;
  if (((lane >> 4) >> 1) == (t & 1)) {
    constexpr int c = t >> 1;
    whiF[c] = *(const short8*)(wb + (lane & 15) * WSTRIDE + c * 32 + (lane >> 4) * 8);
  }
}

// ---------------- fused 128-pivot GJ step + co-scheduled independent work ----------------
// 4 launches (s=0..3), pivot block 128. Grid dim3(4,64)=256 blocks: by<npan ->
// GJ (row-block bx*128, col panel c0=128(s+1)+64*by, processed as 2x32-col
// chunks), else extra slot g = ebase + (by-npan)*4 + bx: g<256 -> gemm-xu
// (launches 0-1), 344<=g<600 -> solve (launches 2-3). Dependencies by stream
// launch order only. Inversion of the 128x128 pivot: 8 stages of 16-panel GJ
// on [M|I] with a 160-col update window per stage (skipped cols have exactly
// zero update -> bit-exact). Dinv = right half of M; MC then overwrites left.
__global__ __launch_bounds__(256) void k_fused(const float* __restrict__ Ain, float* __restrict__ Aout,
                                               ushort* __restrict__ Wfull, int s, int npan, int ebase,
                                               ushort* __restrict__ P, const ushort* __restrict__ Wxu,
                                               float* __restrict__ xu,
                                               const float* __restrict__ D11,
                                               const ushort* __restrict__ D11B,
                                               const float* __restrict__ lam,
                                               const float* __restrict__ bv) {
  __shared__ __align__(16) char smem[152640];  // gj: M[128][260]+sPc[128][36]+pinv ; gemm 48K ; solve 50K
  const int tid = threadIdx.x;
  const int wave = tid >> 6, lane = tid & 63;

  if ((int)blockIdx.y < npan) {
    // =================== 128-pivot GJ body ===================
    float (*M)[260] = (float (*)[260])smem;                       // 133120 B
    float (*sPc)[36] = (float (*)[36])(smem + 133120);            // 18432 B
    float (*pinv)[17] = (float (*)[17])(smem + 133120 + 18432);   // 1088 B
    const int s128 = s * 128, r0 = blockIdx.x * 128;
    const int c0 = s128 + 128 + blockIdx.y * 64;

    // ---- stage pivot block [E_pivot | I] ----
    {
      const int r = tid >> 1, h = (tid & 1) * 64;
      const float* src = Ain + (size_t)(s128 + r) * AUGW + s128 + h;
      #pragma unroll
      for (int c = 0; c < 64; c += 4)
        *(float4*)(&M[r][h + c]) = *(const float4*)(src + c);
      #pragma unroll
      for (int c = 0; c < 64; c += 4)
        *(float4*)(&M[r][128 + h + c]) = make_float4(r == h + c, r == h + c + 1,
                                                     r == h + c + 2, r == h + c + 3);
    }
    __syncthreads();

    // ---- invert 128x128 pivot: 8 stages of 16-panel GJ ----
    for (int t = 0; t < 8; ++t) {
      const int kt = t * 16;
      // phase 1: wave 0 inverts 16x16 diagonal block in registers
      if (wave == 0) {
        const int cc = lane & 31;
        float q[16];
        #pragma unroll
        for (int r = 0; r < 16; ++r)
          q[r] = (cc < 16) ? M[kt + r][kt + cc] : ((r == cc - 16) ? 1.f : 0.f);
        #pragma unroll
        for (int p = 0; p < 16; ++p) {
          float piv = rdlane(q[p], p);
          float rp = __builtin_amdgcn_rcpf(piv);
          rp = rp * (2.f - piv * rp);         // NR: fp32-exact reciprocal
          float a[16];
          #pragma unroll
          for (int r = 0; r < 16; ++r) a[r] = rdlane(q[r], p);
          q[p] *= rp;
          #pragma unroll
          for (int r = 0; r < 16; ++r)
            if (r != p) q[r] = fmaf(-a[r], q[p], q[r]);
        }
        if (lane >= 16 && lane < 32) {
          #pragma unroll
          for (int r = 0; r < 16; ++r) pinv[r][lane - 16] = q[r];
        }
      }
      __syncthreads();
      // phase 2: R = pinv @ M[band t][0:256), overwrite band rows (full width)
      {
        const int ri = tid >> 4, j0 = (tid & 15) * 16;
        float rr[16] = {};
        float a0[16], a1[16], p0, p1v;
        p0 = pinv[ri][0];
        #pragma unroll
        for (int c = 0; c < 16; c += 4)
          *(float4*)(&a0[c]) = *(const float4*)(&M[kt][j0 + c]);
        #pragma unroll
        for (int k = 0; k < 16; k += 2) {
          p1v = pinv[ri][k + 1];
          #pragma unroll
          for (int c = 0; c < 16; c += 4)
            *(float4*)(&a1[c]) = *(const float4*)(&M[kt + k + 1][j0 + c]);
          #pragma unroll
          for (int c = 0; c < 16; ++c) rr[c] = fmaf(p0, a0[c], rr[c]);
          if (k + 2 < 16) {
            p0 = pinv[ri][k + 2];
            #pragma unroll
            for (int c = 0; c < 16; c += 4)
              *(float4*)(&a0[c]) = *(const float4*)(&M[kt + k + 2][j0 + c]);
          }
          #pragma unroll
          for (int c = 0; c < 16; ++c) rr[c] = fmaf(p1v, a1[c], rr[c]);
        }
        __syncthreads();
        #pragma unroll
        for (int c = 0; c < 16; c += 4)
          *(float4*)(&M[kt + ri][j0 + c]) = make_float4(rr[c], rr[c+1], rr[c+2], rr[c+3]);
      }
      __syncthreads();
      // phase 3: eliminate non-band rows over window [cl, cl+160) (exact)
      {
        const int cl = 32 * (t >> 1);
        const int rA = (tid & 63) * 2;
        const int cb = cl + (tid >> 6) * 40;
        const bool act = ((rA >> 4) != t);
        float m0[16], m1[16], o0[40], o1[40];
        if (act) {
          #pragma unroll
          for (int j = 0; j < 16; j += 4) {
            float4 v = *(const float4*)(&M[rA][kt + j]);
            m0[j] = v.x; m0[j+1] = v.y; m0[j+2] = v.z; m0[j+3] = v.w;
            float4 w = *(const float4*)(&M[rA + 1][kt + j]);
            m1[j] = w.x; m1[j+1] = w.y; m1[j+2] = w.z; m1[j+3] = w.w;
          }
          #pragma unroll
          for (int c = 0; c < 40; c += 4) {
            float4 v = *(const float4*)(&M[rA][cb + c]);
            o0[c] = v.x; o0[c+1] = v.y; o0[c+2] = v.z; o0[c+3] = v.w;
            float4 w = *(const float4*)(&M[rA + 1][cb + c]);
            o1[c] = w.x; o1[c+1] = w.y; o1[c+2] = w.z; o1[c+3] = w.w;
          }
        }
        __syncthreads();               // pre-reads done before band-row reads/writes
        if (act) {
          #pragma unroll
          for (int k = 0; k < 16; ++k) {
            float rv[40];
            #pragma unroll
            for (int c = 0; c < 40; c += 4)
              *(float4*)(&rv[c]) = *(const float4*)(&M[kt + k][cb + c]);
            #pragma unroll
            for (int c = 0; c < 40; ++c) {
              o0[c] = fmaf(-m0[k], rv[c], o0[c]);
              o1[c] = fmaf(-m1[k], rv[c], o1[c]);
            }
          }
          #pragma unroll
          for (int c = 0; c < 40; c += 4) {
            *(float4*)(&M[rA][cb + c]) = make_float4(o0[c], o0[c+1], o0[c+2], o0[c+3]);
            *(float4*)(&M[rA + 1][cb + c]) = make_float4(o1[c], o1[c+1], o1[c+2], o1[c+3]);
          }
        }
      }
      __syncthreads();
    }

    // ---- overwrite left half with MC = Ain[r0 rows][pivot cols] ----
    {
      const int r = tid >> 1, h = (tid & 1) * 64;
      const float* src = Ain + (size_t)(r0 + r) * AUGW + s128 + h;
      #pragma unroll
      for (int c = 0; c < 64; c += 4)
        *(float4*)(&M[r][h + c]) = *(const float4*)(src + c);
    }
    __syncthreads();

    // ---- per 32-col chunk: PB = Dinv@sP ; out = av - MC@PB (pivot rows: PB) ----
    const int R4b = (tid >> 3) * 4, C4b = (tid & 7) * 4;
    #pragma unroll
    for (int ch = 0; ch < 2; ++ch) {
      const int cc0 = c0 + ch * 32;
      {
        const int k = tid >> 1, h16 = (tid & 1) * 16;
        const float* src = Ain + (size_t)(s128 + k) * AUGW + cc0 + h16;
        #pragma unroll
        for (int c = 0; c < 16; c += 4)
          *(float4*)(&sPc[k][h16 + c]) = *(const float4*)(src + c);
      }
      __syncthreads();
      float pb[4][4] = {{0.f,0.f,0.f,0.f},{0.f,0.f,0.f,0.f},{0.f,0.f,0.f,0.f},{0.f,0.f,0.f,0.f}};
      for (int k4 = 0; k4 < 128; k4 += 4) {
        float dva[4][4], spa[4][4];
        #pragma unroll
        for (int r = 0; r < 4; ++r) {
          float4 v = *(const float4*)(&M[R4b + r][128 + k4]);
          dva[r][0] = v.x; dva[r][1] = v.y; dva[r][2] = v.z; dva[r][3] = v.w;
        }
        #pragma unroll
        for (int kk = 0; kk < 4; ++kk) {
          float4 v = *(const float4*)(&sPc[k4 + kk][C4b]);
          spa[kk][0] = v.x; spa[kk][1] = v.y; spa[kk][2] = v.z; spa[kk][3] = v.w;
        }
        #pragma unroll
        for (int kk = 0; kk < 4; ++kk)
          #pragma unroll
          for (int r = 0; r < 4; ++r)
            #pragma unroll
            for (int c = 0; c < 4; ++c)
              pb[r][c] = fmaf(dva[r][kk], spa[kk][c], pb[r][c]);
      }
      __syncthreads();
      #pragma unroll
      for (int r = 0; r < 4; ++r)
        *(float4*)(&sPc[R4b + r][C4b]) = make_float4(pb[r][0], pb[r][1], pb[r][2], pb[r][3]);
      __syncthreads();
      float o[4][4];
      if (blockIdx.x == (unsigned)s) {
        #pragma unroll
        for (int r = 0; r < 4; ++r)
          #pragma unroll
          for (int c = 0; c < 4; ++c) o[r][c] = pb[r][c];
      } else {
        #pragma unroll
        for (int r = 0; r < 4; ++r) {
          float4 v = *(const float4*)(Ain + (size_t)(r0 + R4b + r) * AUGW + cc0 + C4b);
          o[r][0] = v.x; o[r][1] = v.y; o[r][2] = v.z; o[r][3] = v.w;
        }
        for (int k4 = 0; k4 < 128; k4 += 4) {
          float mca[4][4], spa[4][4];
          #pragma unroll
          for (int r = 0; r < 4; ++r) {
            float4 v = *(const float4*)(&M[R4b + r][k4]);
            mca[r][0] = v.x; mca[r][1] = v.y; mca[r][2] = v.z; mca[r][3] = v.w;
          }
          #pragma unroll
          for (int kk = 0; kk < 4; ++kk) {
            float4 v = *(const float4*)(&sPc[k4 + kk][C4b]);
            spa[kk][0] = v.x; spa[kk][1] = v.y; spa[kk][2] = v.z; spa[kk][3] = v.w;
          }
          #pragma unroll
          for (int kk = 0; kk < 4; ++kk)
            #pragma unroll
            for (int r = 0; r < 4; ++r)
              #pragma unroll
              for (int c = 0; c < 4; ++c)
                o[r][c] = fmaf(-mca[r][kk], spa[kk][c], o[r][c]);
        }
      }
      if (s == 3) {                   // all trailing cols >= 512 -> Wfull bf16
        int k0 = cc0 - 512 + C4b;
        #pragma unroll
        for (int r = 0; r < 4; ++r) {
          ushort4 h = { f2bf(o[r][0]), f2bf(o[r][1]), f2bf(o[r][2]), f2bf(o[r][3]) };
          *(ushort4*)(Wfull + (size_t)(r0 + R4b + r) * KP + k0) = h;
        }
      } else {
        #pragma unroll
        for (int r = 0; r < 4; ++r)
          *(float4*)(Aout + (size_t)(r0 + R4b + r) * AUGW + cc0 + C4b) =
              make_float4(o[r][0], o[r][1], o[r][2], o[r][3]);
      }
      __syncthreads();                 // sPc reuse in next chunk
    }
    return;
  }

  // =================== extra blocks: independent-chain slices ===================
  const int g = ebase + ((int)blockIdx.y - npan) * 4 + (int)blockIdx.x;

  if (g < 256) {
    // ---- gemm-xu slice: xu[m][n] = sum_k P[m][k] * Wxu[n][k] ----
    ushort* sA = (ushort*)smem;            // 3 * 4096 ushorts
    ushort* sB = (ushort*)(smem + 24576);
    const int mb = g >> 1, nb = g & 1;
    int wm = wave & 1, wn = wave >> 1;
    int m0 = mb * 128, n0 = nb * 128;
    int r16 = lane & 15, kq = lane >> 4;
    int lrow = lane >> 2, lseg = lane & 3;
    const ushort* gA0 = P + (size_t)(m0 + wave * 32 + lrow) * KP + lseg * 8;
    const ushort* gA1 = gA0 + 16 * KP;
    const ushort* gB0 = Wxu + (size_t)(n0 + wave * 32 + lrow) * KP + lseg * 8;
    const ushort* gB1 = gB0 + 16 * KP;

    #define STAGE_KB(bi, kb_)                                              \
      do {                                                                 \
        GLOAD_LDS16(gA0 + (kb_) * 32, sA + (bi) * 4096 + wave * 1024);     \
        GLOAD_LDS16(gA1 + (kb_) * 32, sA + (bi) * 4096 + wave * 1024 + 512); \
        GLOAD_LDS16(gB0 + (kb_) * 32, sB + (bi) * 4096 + wave * 1024);     \
        GLOAD_LDS16(gB1 + (kb_) * 32, sB + (bi) * 4096 + wave * 1024 + 512); \
      } while (0)

    f32x4 acc[4][4] = {};
    const int NKB = KP / 32;   // 32
    STAGE_KB(0, 0);
    STAGE_KB(1, 1);
    #pragma unroll
    for (int kb = 0; kb < NKB; ++kb) {
      const int bi = kb % 3;
      if (kb + 2 < NKB) {
        STAGE_KB((kb + 2) % 3, kb + 2);
        asm volatile("s_waitcnt vmcnt(8)" ::: "memory");
      } else if (kb + 2 == NKB) {
        asm volatile("s_waitcnt vmcnt(4)" ::: "memory");
      } else {
        asm volatile("s_waitcnt vmcnt(0)" ::: "memory");
      }
      __builtin_amdgcn_s_barrier();
      __builtin_amdgcn_sched_barrier(0);
      short8 af[4], bf[4];
      #pragma unroll
      for (int t = 0; t < 4; ++t) {
        af[t] = *(const short8*)(sA + bi * 4096 + (wm * 64 + t * 16 + r16) * 32 + kq * 8);
        bf[t] = *(const short8*)(sB + bi * 4096 + (wn * 64 + t * 16 + r16) * 32 + kq * 8);
      }
      #pragma unroll
      for (int mt = 0; mt < 4; ++mt)
        #pragma unroll
        for (int nt = 0; nt < 4; ++nt)
          acc[mt][nt] = __builtin_amdgcn_mfma_f32_16x16x32_bf16(af[mt], bf[nt], acc[mt][nt], 0, 0, 0);
      __builtin_amdgcn_sched_barrier(0);
      __builtin_amdgcn_s_barrier();
    }
    #undef STAGE_KB

    #pragma unroll
    for (int mt = 0; mt < 4; ++mt)
      #pragma unroll
      for (int nt = 0; nt < 4; ++nt)
        #pragma unroll
        for (int i = 0; i < 4; ++i) {
          int m = m0 + wm * 64 + mt * 16 + kq * 4 + i;
          int n = n0 + wn * 64 + nt * 16 + r16;
          xu[(size_t)m * NQq + n] = acc[mt][nt][i];
        }
    return;
  }

  if (g >= 344 && g < 600) {
    // ---- solve slice (launches 2-3; xu complete end of launch 1) ----
    const int sid = g - 344;
    ushort* wB = (ushort*)smem;                               // 4*16*WSTRIDE ushorts
    float (*d11T)[16][16] = (float (*)[16][16])(smem + 33792);
    const int r0w = sid * 64 + wave * 16;
    const int bp4 = (((lane >> 2) | ((lane & 3) << 4)) << 2); // bpermute byte addr
    for (int i = tid; i < 4096; i += 256) {
      int tt = i >> 8, j = (i >> 4) & 15, c = i & 15;
      d11T[tt][j][c] = (c > j) ? D11[(size_t)(tt * 16 + c) * NQq + tt * 16 + j] : 0.f;
    }
    Pre pre0, pre1;
    tile_loads<0>(xu, D11B, lam, bv, lane, r0w, pre0);
    __syncthreads();                          // the only block-wide barrier
    ushort* wb = wB + wave * 16 * WSTRIDE;
    short8 whiF[8] = {};
    do_tile<0>(xu, D11B, lam, bv, wb, d11T, whiF, lane, bp4, r0w, pre0, pre1);
    do_tile<1>(xu, D11B, lam, bv, wb, d11T, whiF, lane, bp4, r0w, pre1, pre0);
    do_tile<2>(xu, D11B, lam, bv, wb, d11T, whiF, lane, bp4, r0w, pre0, pre1);
    do_tile<3>(xu, D11B, lam, bv, wb, d11T, whiF, lane, bp4, r0w, pre1, pre0);
    do_tile<4>(xu, D11B, lam, bv, wb, d11T, whiF, lane, bp4, r0w, pre0, pre1);
    do_tile<5>(xu, D11B, lam, bv, wb, d11T, whiF, lane, bp4, r0w, pre1, pre0);
    do_tile<6>(xu, D11B, lam, bv, wb, d11T, whiF, lane, bp4, r0w, pre0, pre1);
    do_tile<7>(xu, D11B, lam, bv, wb, d11T, whiF, lane, bp4, r0w, pre1, pre0);
    do_tile<8>(xu, D11B, lam, bv, wb, d11T, whiF, lane, bp4, r0w, pre0, pre1);
    do_tile<9>(xu, D11B, lam, bv, wb, d11T, whiF, lane, bp4, r0w, pre1, pre0);
    do_tile<10>(xu, D11B, lam, bv, wb, d11T, whiF, lane, bp4, r0w, pre0, pre1);
    do_tile<11>(xu, D11B, lam, bv, wb, d11T, whiF, lane, bp4, r0w, pre1, pre0);
    do_tile<12>(xu, D11B, lam, bv, wb, d11T, whiF, lane, bp4, r0w, pre0, pre1);
    do_tile<13>(xu, D11B, lam, bv, wb, d11T, whiF, lane, bp4, r0w, pre1, pre0);
    do_tile<14>(xu, D11B, lam, bv, wb, d11T, whiF, lane, bp4, r0w, pre0, pre1);
    do_tile<15>(xu, D11B, lam, bv, wb, d11T, whiF, lane, bp4, r0w, pre1, pre0);
    #pragma unroll
    for (int it = 0; it < 8; ++it) {
      int f = it * 64 + lane;
      int m = f >> 5, k8 = f & 31;
      uint4 v = *(const uint4*)(wb + m * WSTRIDE + k8 * 8);
      *(uint4*)(P + (size_t)(r0w + m) * KP + NXq + k8 * 8) = v;
    }
    return;
  }
  // remaining extras: idle
}

// ---------------- bf16 MFMA GEMM (final dx,y): out[m][n] = sum_k P[m][k] * W[n][k] ----------------
__global__ __launch_bounds__(256) void k_gemm(const ushort* __restrict__ P, const ushort* __restrict__ W,
                                              float* __restrict__ out) {
  __shared__ ushort sA[3][128 * 32];
  __shared__ ushort sB[3][128 * 32];
  int tid = threadIdx.x;
  int lane = tid & 63, wave = tid >> 6;
  int wm = wave & 1, wn = wave >> 1;
  int m0 = blockIdx.x * 128;
  int n0 = blockIdx.y * 128;
  int r16 = lane & 15, kq = lane >> 4;
  int lrow = lane >> 2, lseg = lane & 3;
  const ushort* gA0 = P + (size_t)(m0 + wave * 32 + lrow) * KP + lseg * 8;
  const ushort* gA1 = gA0 + 16 * KP;
  const ushort* gB0 = W + (size_t)(n0 + wave * 32 + lrow) * KP + lseg * 8;
  const ushort* gB1 = gB0 + 16 * KP;

  #define STAGE_KB(bi, kb_)                                        \
    do {                                                           \
      GLOAD_LDS16(gA0 + (kb_) * 32, &sA[bi][wave * 1024]);         \
      GLOAD_LDS16(gA1 + (kb_) * 32, &sA[bi][wave * 1024 + 512]);   \
      GLOAD_LDS16(gB0 + (kb_) * 32, &sB[bi][wave * 1024]);         \
      GLOAD_LDS16(gB1 + (kb_) * 32, &sB[bi][wave * 1024 + 512]);   \
    } while (0)

  f32x4 acc[4][4] = {};
  const int NKB = KP / 32;   // 32
  STAGE_KB(0, 0);
  STAGE_KB(1, 1);
  #pragma unroll
  for (int kb = 0; kb < NKB; ++kb) {
    const int bi = kb % 3;
    if (kb + 2 < NKB) {
      STAGE_KB((kb + 2) % 3, kb + 2);
      asm volatile("s_waitcnt vmcnt(8)" ::: "memory");   // stage kb (own 4 loads) done
    } else if (kb + 2 == NKB) {
      asm volatile("s_waitcnt vmcnt(4)" ::: "memory");
    } else {
      asm volatile("s_waitcnt vmcnt(0)" ::: "memory");
    }
    __builtin_amdgcn_s_barrier();          // all waves' stage kb complete
    __builtin_amdgcn_sched_barrier(0);     // pin: no ds_read hoists above barrier
    short8 af[4], bf[4];
    #pragma unroll
    for (int t = 0; t < 4; ++t) {
      af[t] = *(const short8*)(&sA[bi][(wm * 64 + t * 16 + r16) * 32 + kq * 8]);
      bf[t] = *(const short8*)(&sB[bi][(wn * 64 + t * 16 + r16) * 32 + kq * 8]);
    }
    #pragma unroll
    for (int mt = 0; mt < 4; ++mt)
      #pragma unroll
      for (int nt = 0; nt < 4; ++nt)
        acc[mt][nt] = __builtin_amdgcn_mfma_f32_16x16x32_bf16(af[mt], bf[nt], acc[mt][nt], 0, 0, 0);
    __builtin_amdgcn_sched_barrier(0);     // pin: reads complete before end barrier
    __builtin_amdgcn_s_barrier();          // reads of buf bi done before overwrite
  }
  #undef STAGE_KB

  #pragma unroll
  for (int mt = 0; mt < 4; ++mt)
    #pragma unroll
    for (int nt = 0; nt < 4; ++nt)
      #pragma unroll
      for (int i = 0; i < 4; ++i) {
        int m = m0 + wm * 64 + mt * 16 + kq * 4 + i;
        int n = n0 + wn * 64 + nt * 16 + r16;
        float val = acc[mt][nt][i];
        if (n < NXq) out[(size_t)m * NXq + n] = val;
        else out[(size_t)NBq * NXq + (size_t)m * NYq + (n - NXq)] = val;
      }
}

extern "C" void kernel_launch(void* const* d_in, const int* in_sizes, int n_in,
                              void* d_out, int out_size, void* d_ws, size_t ws_size,
                              hipStream_t stream) {
  const float* x   = (const float*)d_in[0];
  const float* u   = (const float*)d_in[1];
  const float* F   = (const float*)d_in[2];
  const float* B1  = (const float*)d_in[3];
  const float* B2  = (const float*)d_in[4];
  const float* C1  = (const float*)d_in[5];
  const float* C2  = (const float*)d_in[6];
  const float* D11 = (const float*)d_in[7];
  const float* D12 = (const float*)d_in[8];
  const float* D21 = (const float*)d_in[9];
  const float* E   = (const float*)d_in[10];
  const float* lam = (const float*)d_in[11];
  const float* bv  = (const float*)d_in[12];

  char* ws = (char*)d_ws;
  ushort* P    = (ushort*)ws;                                     // 32 MB
  float* xu    = (float*)(ws + (size_t)(32u << 20));              // 16 MB
  float* AUG0  = (float*)(ws + (size_t)(48u << 20));              // 3 MB
  float* AUG1  = (float*)(ws + (size_t)(52u << 20));              // 3 MB
  ushort* Wfull = (ushort*)(ws + (size_t)(56u << 20));            // 1.25 MB bf16
  ushort* Wxu   = (ushort*)(ws + (size_t)(58u << 20));            // 0.5 MB bf16
  ushort* D11B  = (ushort*)(ws + (size_t)(59u << 20));            // 128 KB bf16
  float* out   = (float*)d_out;
  float* AUGbuf[2] = { AUG0, AUG1 };

  // 128-pivot: 4 steps; panels of 64 cols; extras host gemm-xu then solve.
  static const int npan_tab[4]  = {22, 20, 18, 16};
  static const int ebase_tab[4] = {0, 168, 344, 528};

  k_prep<<<17152, 256, 0, stream>>>(x, u, E, F, B1, B2, C1, C2, D11, D12, D21,
                                    P, AUG0, Wxu, D11B, Wfull);
  for (int s = 0; s < 4; ++s)
    k_fused<<<dim3(4, 64), 256, 0, stream>>>(AUGbuf[s & 1], AUGbuf[(s + 1) & 1],
                                             Wfull, s, npan_tab[s], ebase_tab[s],
                                             P, Wxu, xu, D11, D11B, lam, bv);
  k_gemm<<<dim3(128, 5), 256, 0, stream>>>(P, Wfull, out);        // dx, y
}

// Round 10
// 325.128 us; speedup vs baseline: 1.4175x; 1.4175x over previous
//
#include <hip/hip_runtime.h>

#define NBq 16384
#define NXq 512
#define NUq 256
#define NYq 128
#define NQq 256
#define KP  1024   // P width: [x(512) | w(256) | u(256)]
#define AUGW 1536  // [E(512) | F(512) | B1(256) | B2(256)]

typedef __attribute__((ext_vector_type(8))) short short8;
typedef __attribute__((ext_vector_type(4))) float f32x4;

__device__ __forceinline__ ushort f2bf(float f) {
  uint x = __float_as_uint(f);
  x += 0x7FFFu + ((x >> 16) & 1u);   // RNE
  return (ushort)(x >> 16);
}

// async global->LDS, 16B per lane; LDS dest is wave-uniform base + lane*16
#define GLOAD_LDS16(g, l)                                             \
  __builtin_amdgcn_global_load_lds(                                   \
      (const __attribute__((address_space(1))) void*)(g),             \
      (__attribute__((address_space(3))) void*)(l), 16, 0, 0)

__device__ __forceinline__ float rdlane(float x, int l) {
  return __int_as_float(__builtin_amdgcn_readlane(__float_as_int(x), l));
}

// ---------------- fused prep: pack x,u -> P ; AUG ; Wxu ; D11B ; Wfull static rows ----------------
__global__ __launch_bounds__(256) void k_prep(const float* __restrict__ x, const float* __restrict__ u,
                                              const float* __restrict__ E, const float* __restrict__ F,
                                              const float* __restrict__ B1, const float* __restrict__ B2,
                                              const float* __restrict__ C1, const float* __restrict__ C2,
                                              const float* __restrict__ D11, const float* __restrict__ D12,
                                              const float* __restrict__ D21,
                                              ushort* __restrict__ P, float* __restrict__ AUG,
                                              ushort* __restrict__ Wxu, ushort* __restrict__ D11B,
                                              ushort* __restrict__ Wfull) {
  int b = blockIdx.x, tid = threadIdx.x;
  if (b < 12288) {                       // pack x,u (float4 -> bf16x4)
    int idx = b * 256 + tid;
    const int nx4 = NBq * NXq / 4;
    if (idx < nx4) {
      float4 v = *(const float4*)(x + (size_t)idx * 4);
      int row = idx >> 7, c4 = idx & 127;
      ushort4 h = { f2bf(v.x), f2bf(v.y), f2bf(v.z), f2bf(v.w) };
      *(ushort4*)(P + (size_t)row * KP + c4 * 4) = h;
    } else {
      int i = idx - nx4;
      float4 v = *(const float4*)(u + (size_t)i * 4);
      int row = i >> 6, c4 = i & 63;
      ushort4 h = { f2bf(v.x), f2bf(v.y), f2bf(v.z), f2bf(v.w) };
      *(ushort4*)(P + (size_t)row * KP + 768 + c4 * 4) = h;
    }
  } else if (b < 15360) {                // AUG = [E | F B1 B2]
    int idx = (b - 12288) * 256 + tid;
    int r = idx / AUGW, c = idx % AUGW;
    float v;
    if (c < 512)       v = E[r * 512 + c];
    else if (c < 1024) v = F[r * 512 + (c - 512)];
    else if (c < 1280) v = B1[r * 256 + (c - 1024)];
    else               v = B2[r * 256 + (c - 1280)];
    AUG[idx] = v;
  } else if (b < 16384) {                // Wxu = [C1 | 0 | D12] bf16
    int idx = (b - 15360) * 256 + tid;
    int r = idx >> 10, k = idx & 1023;
    float v;
    if (k < 512)      v = C1[r * 512 + k];
    else if (k < 768) v = 0.f;
    else              v = D12[r * 256 + (k - 768)];
    Wxu[idx] = f2bf(v);
  } else if (b < 16640) {                // D11 -> bf16
    int idx = (b - 16384) * 256 + tid;
    D11B[idx] = f2bf(D11[idx]);
  } else {                               // Wfull rows 512..639 = [C2 | D21 | 0]
    int idx = (b - 16640) * 256 + tid;   // < 131072
    int j = idx >> 10, k = idx & 1023;
    float v;
    if (k < 512)      v = C2[j * 512 + k];
    else if (k < 768) v = D21[j * 256 + (k - 512)];
    else              v = 0.f;
    Wfull[(size_t)(512 + j) * KP + k] = f2bf(v);
  }
}

// ---------------- solve helpers (MFMA tanh forward substitution, lane-local) ----------------
#define WSTRIDE 264
#define TANH_K 2.8853900817779268f   // 2*log2(e): exp(2v) = exp2(v*TANH_K)

struct Pre {
  f32x4 xuv;        // C-in: xu[r0w + (lane&15)][kt + 4*(lane>>4) + 0..3]
  short8 b[8];      // D11B fragments (A-operand)
  f32x4 rl2, bv2;   // per serial col 4*(lane&3)+i: TANH_K/lam, bv*TANH_K/lam
};

template<int t>
__device__ __forceinline__ void tile_loads(const float* __restrict__ xu,
                                           const ushort* __restrict__ D11B,
                                           const float* __restrict__ lam,
                                           const float* __restrict__ bv,
                                           int lane, int r0w, Pre& pre) {
  constexpr int kt = t * 16;
  constexpr int cmax = (t + 1) >> 1;
  const int mr = lane & 15, kq = lane >> 4, q = lane & 3;
  pre.xuv = *(const f32x4*)(&xu[(size_t)(r0w + mr) * NQq + kt + kq * 4]);
  #pragma unroll
  for (int c = 0; c < cmax; ++c)
    pre.b[c] = *(const short8*)(D11B + (size_t)(kt + mr) * NQq + c * 32 + kq * 8);
  float4 l4 = *(const float4*)(&lam[kt + q * 4]);
  float4 b4 = *(const float4*)(&bv[kt + q * 4]);
  pre.rl2[0] = TANH_K / l4.x; pre.rl2[1] = TANH_K / l4.y;
  pre.rl2[2] = TANH_K / l4.z; pre.rl2[3] = TANH_K / l4.w;
  pre.bv2[0] = b4.x * pre.rl2[0]; pre.bv2[1] = b4.y * pre.rl2[1];
  pre.bv2[2] = b4.z * pre.rl2[2]; pre.bv2[3] = b4.w * pre.rl2[3];
}

// one serial step: broadcast w[col k-1] within the quad, rank-1 update, tanh.
#define SOLVE_STEP(k, dvreg)                                                   \
  {                                                                            \
    float wb_ = __int_as_float(__builtin_amdgcn_update_dpp(                    \
        0, __float_as_int(wreg), (((k - 1) >> 2) * 0x55), 0xF, 0xF, true));    \
    acc[0] = fmaf(dvreg.x, wb_, acc[0]);                                       \
    acc[1] = fmaf(dvreg.y, wb_, acc[1]);                                       \
    acc[2] = fmaf(dvreg.z, wb_, acc[2]);                                       \
    acc[3] = fmaf(dvreg.w, wb_, acc[3]);                                       \
    if constexpr ((k) + 3 <= 14) dvreg = *(const float4*)(&dT[(k) + 3][q4]);   \
    float v_ = fmaf(acc[(k) & 3], rl2[(k) & 3], bv2[(k) & 3]);                 \
    float e_ = __builtin_amdgcn_exp2f(v_);                                     \
    float w_ = fmaf(-2.f, __builtin_amdgcn_rcpf(1.f + e_), 1.f);               \
    wreg = w_;                                                                 \
    if (q == ((k) >> 2)) wk[(k) & 3] = w_;                                     \
  }

template<int t>
__device__ __forceinline__ void do_tile(const float* __restrict__ xu,
                                        const ushort* __restrict__ D11B,
                                        const float* __restrict__ lam,
                                        const float* __restrict__ bv,
                                        ushort* wb, const float (*d11T)[16][16],
                                        short8 (&whiF)[8], int lane, int bp4,
                                        int r0w, Pre& cur, Pre& nxt) {
  constexpr int kt = t * 16;
  constexpr int cmax = (t + 1) >> 1;
  if constexpr (t < 15)
    tile_loads<t + 1>(xu, D11B, lam, bv, lane, r0w, nxt);
  const int q = lane & 3, r2 = lane >> 2;
  const int q4 = q * 4;
  const float (*dT)[16] = d11T[t];
  float4 dvb0 = *(const float4*)(&dT[0][q4]);
  float4 dvb1 = *(const float4*)(&dT[1][q4]);
  float4 dvb2 = *(const float4*)(&dT[2][q4]);
  float4 dvb3 = *(const float4*)(&dT[3][q4]);
  f32x4 accM = cur.xuv;
  #pragma unroll
  for (int c = 0; c < cmax; ++c)
    accM = __builtin_amdgcn_mfma_f32_16x16x32_bf16(cur.b[c], whiF[c], accM, 0, 0, 0);
  f32x4 acc;
  acc[0] = __int_as_float(__builtin_amdgcn_ds_bpermute(bp4, __float_as_int(accM[0])));
  acc[1] = __int_as_float(__builtin_amdgcn_ds_bpermute(bp4, __float_as_int(accM[1])));
  acc[2] = __int_as_float(__builtin_amdgcn_ds_bpermute(bp4, __float_as_int(accM[2])));
  acc[3] = __int_as_float(__builtin_amdgcn_ds_bpermute(bp4, __float_as_int(accM[3])));
  const f32x4 rl2 = cur.rl2, bv2 = cur.bv2;
  float wreg = 0.f, wk[4] = {0.f, 0.f, 0.f, 0.f};
  {  // step 0
    float v_ = fmaf(acc[0], rl2[0], bv2[0]);
    float e_ = __builtin_amdgcn_exp2f(v_);
    float w_ = fmaf(-2.f, __builtin_amdgcn_rcpf(1.f + e_), 1.f);
    wreg = w_;
    if (q == 0) wk[0] = w_;
  }
  SOLVE_STEP(1, dvb0)
  SOLVE_STEP(2, dvb1)
  SOLVE_STEP(3, dvb2)
  SOLVE_STEP(4, dvb3)
  SOLVE_STEP(5, dvb0)
  SOLVE_STEP(6, dvb1)
  SOLVE_STEP(7, dvb2)
  SOLVE_STEP(8, dvb3)
  SOLVE_STEP(9, dvb0)
  SOLVE_STEP(10, dvb1)
  SOLVE_STEP(11, dvb2)
  SOLVE_STEP(12, dvb3)
  SOLVE_STEP(13, dvb0)
  SOLVE_STEP(14, dvb1)
  SOLVE_STEP(15, dvb2)
  ushort4 h = { f2bf(wk[0]), f2bf(wk[1]), f2bf(wk[2]), f2bf(wk[3]) };
  *(ushort4*)(wb + r2 * WSTRIDE + kt + q * 4) = h;
  if (((lane >> 4) >> 1) == (t & 1)) {
    constexpr int c = t >> 1;
    whiF[c] = *(const short8*)(wb + (lane & 15) * WSTRIDE + c * 32 + (lane >> 4) * 8);
  }
}

// ---------------- fused GJ step + co-scheduled independent work ----------------
// Grid dim3(8,32) = 256 blocks. Blocks with by < 23-s do the GJ step (identical
// math to the passing 8-launch v4). Extra blocks (by >= 23-s) run slices of the
// INDEPENDENT chain on otherwise-idle CUs: global extra-slot id
// g = ebase + (by-nby)*8 + bx;  g<256 -> gemm-xu block (launches 0-3, xu fully
// written by end of launch 3);  336<=g<592 -> solve block (launches 4-6).
// Dependencies honored purely by stream launch ordering; no new sync.
__global__ __launch_bounds__(256) void k_fused(const float* __restrict__ Ain, float* __restrict__ Aout,
                                               ushort* __restrict__ Wfull, int s, int ebase,
                                               ushort* __restrict__ P, const ushort* __restrict__ Wxu,
                                               float* __restrict__ xu,
                                               const float* __restrict__ D11,
                                               const ushort* __restrict__ D11B,
                                               const float* __restrict__ lam,
                                               const float* __restrict__ bv) {
  __shared__ __align__(16) char smem[69696];   // union: gj 69.7K / gemm 48K / solve 49K
  const int tid = threadIdx.x;
  const int wave = tid >> 6, lane = tid & 63;
  const int nby = 23 - s;
  const int last = (s == 7);

  if ((int)blockIdx.y < nby) {
    // =================== GJ body (byte-identical math to 8-launch v4) ===================
    float (*M)[132] = (float (*)[132])smem;
    float (*sP)[68] = (float (*)[68])(smem + 33792);
    float (*sMC)[68] = (float (*)[68])(smem + 33792 + 17408);
    float (*pinv)[17] = (float (*)[17])(smem + 33792 + 2 * 17408);
    const int s64 = s * 64, r0 = blockIdx.x * 64, c0 = (s + 1 + blockIdx.y) * 64;
    const int r2 = tid >> 2, cq = (tid & 3) * 16;
    const int R4 = (tid >> 4) * 4;
    const int C4 = (tid & 15) * 4;
    const int C8 = (tid & 15) * 8;

    float av4[4][4];
    #pragma unroll
    for (int r = 0; r < 4; ++r) {
      float4 v = *(const float4*)(Ain + (size_t)(r0 + R4 + r) * AUGW + c0 + C4);
      av4[r][0] = v.x; av4[r][1] = v.y; av4[r][2] = v.z; av4[r][3] = v.w;
    }
    #pragma unroll
    for (int c4 = 0; c4 < 4; ++c4) {
      *(float4*)(&sP[r2][cq + c4 * 4]) =
          *(const float4*)(Ain + (size_t)(s64 + r2) * AUGW + c0 + cq + c4 * 4);
      *(float4*)(&sMC[r2][cq + c4 * 4]) =
          *(const float4*)(Ain + (size_t)(r0 + r2) * AUGW + s64 + cq + c4 * 4);
      *(float4*)(&M[r2][cq + c4 * 4]) =
          *(const float4*)(Ain + (size_t)(s64 + r2) * AUGW + s64 + cq + c4 * 4);
    }
    #pragma unroll
    for (int c = 0; c < 16; ++c)
      M[r2][64 + cq + c] = (r2 == cq + c) ? 1.f : 0.f;
    __syncthreads();

    for (int t = 0; t < 4; ++t) {
      const int kt = t * 16;
      if (wave == 0) {
        const int cc = lane & 31;
        float q[16];
        #pragma unroll
        for (int r = 0; r < 16; ++r)
          q[r] = (cc < 16) ? M[kt + r][kt + cc] : ((r == cc - 16) ? 1.f : 0.f);
        #pragma unroll
        for (int p = 0; p < 16; ++p) {
          float piv = rdlane(q[p], p);
          float rp = __builtin_amdgcn_rcpf(piv);
          rp = rp * (2.f - piv * rp);         // NR: fp32-exact reciprocal
          float a[16];
          #pragma unroll
          for (int r = 0; r < 16; ++r) a[r] = rdlane(q[r], p);
          q[p] *= rp;
          #pragma unroll
          for (int r = 0; r < 16; ++r)
            if (r != p) q[r] = fmaf(-a[r], q[p], q[r]);
        }
        if (lane >= 16 && lane < 32) {
          #pragma unroll
          for (int r = 0; r < 16; ++r) pinv[r][lane - 16] = q[r];
        }
      }
      __syncthreads();
      {
        const int ri = tid >> 4, j0 = (tid & 15) * 8;
        float rr[8] = {};
        float a0[8], a1[8], p0, p1;
        p0 = pinv[ri][0];
        #pragma unroll
        for (int c = 0; c < 8; c += 4)
          *(float4*)(&a0[c]) = *(const float4*)(&M[kt][j0 + c]);
        #pragma unroll
        for (int k = 0; k < 16; k += 2) {
          p1 = pinv[ri][k + 1];
          #pragma unroll
          for (int c = 0; c < 8; c += 4)
            *(float4*)(&a1[c]) = *(const float4*)(&M[kt + k + 1][j0 + c]);
          #pragma unroll
          for (int c = 0; c < 8; ++c) rr[c] = fmaf(p0, a0[c], rr[c]);
          if (k + 2 < 16) {
            p0 = pinv[ri][k + 2];
            #pragma unroll
            for (int c = 0; c < 8; c += 4)
              *(float4*)(&a0[c]) = *(const float4*)(&M[kt + k + 2][j0 + c]);
          }
          #pragma unroll
          for (int c = 0; c < 8; ++c) rr[c] = fmaf(p1, a1[c], rr[c]);
        }
        __syncthreads();
        #pragma unroll
        for (int c = 0; c < 8; c += 4)
          *(float4*)(&M[kt + ri][j0 + c]) = make_float4(rr[c], rr[c+1], rr[c+2], rr[c+3]);
      }
      __syncthreads();
      {
        const bool act = (wave != t);
        float mult[4][16], o2[4][8];
        if (act) {
          #pragma unroll
          for (int r = 0; r < 4; ++r) {
            #pragma unroll
            for (int j = 0; j < 4; ++j) {
              float4 m4 = *(const float4*)(&M[R4 + r][kt + 4 * j]);
              mult[r][4*j+0] = m4.x; mult[r][4*j+1] = m4.y;
              mult[r][4*j+2] = m4.z; mult[r][4*j+3] = m4.w;
            }
            float4 a = *(const float4*)(&M[R4 + r][C8]);
            float4 b = *(const float4*)(&M[R4 + r][C8 + 4]);
            o2[r][0] = a.x; o2[r][1] = a.y; o2[r][2] = a.z; o2[r][3] = a.w;
            o2[r][4] = b.x; o2[r][5] = b.y; o2[r][6] = b.z; o2[r][7] = b.w;
          }
        }
        __syncthreads();               // all pre-update reads done before writes
        if (act) {
          float rv[2][8];
          {
            float4 a = *(const float4*)(&M[kt][C8]);
            float4 b = *(const float4*)(&M[kt][C8 + 4]);
            rv[0][0] = a.x; rv[0][1] = a.y; rv[0][2] = a.z; rv[0][3] = a.w;
            rv[0][4] = b.x; rv[0][5] = b.y; rv[0][6] = b.z; rv[0][7] = b.w;
          }
          #pragma unroll
          for (int k = 0; k < 16; ++k) {
            if (k + 1 < 16) {
              float4 a = *(const float4*)(&M[kt + k + 1][C8]);
              float4 b = *(const float4*)(&M[kt + k + 1][C8 + 4]);
              rv[(k+1)&1][0] = a.x; rv[(k+1)&1][1] = a.y;
              rv[(k+1)&1][2] = a.z; rv[(k+1)&1][3] = a.w;
              rv[(k+1)&1][4] = b.x; rv[(k+1)&1][5] = b.y;
              rv[(k+1)&1][6] = b.z; rv[(k+1)&1][7] = b.w;
            }
            #pragma unroll
            for (int r = 0; r < 4; ++r)
              #pragma unroll
              for (int c = 0; c < 8; ++c)
                o2[r][c] = fmaf(-mult[r][k], rv[k&1][c], o2[r][c]);
          }
          #pragma unroll
          for (int r = 0; r < 4; ++r) {
            *(float4*)(&M[R4 + r][C8]) =
                make_float4(o2[r][0], o2[r][1], o2[r][2], o2[r][3]);
            *(float4*)(&M[R4 + r][C8 + 4]) =
                make_float4(o2[r][4], o2[r][5], o2[r][6], o2[r][7]);
          }
        }
      }
      __syncthreads();
    }

    #define LOADCH_PB(dv, sv, ch)                                             \
      do {                                                                    \
        const int q0_ = (ch) * 4;                                             \
        _Pragma("unroll")                                                     \
        for (int r_ = 0; r_ < 4; ++r_) {                                      \
          float4 d_ = *(const float4*)(&M[R4 + r_][64 + q0_]);                \
          dv[r_][0] = d_.x; dv[r_][1] = d_.y; dv[r_][2] = d_.z; dv[r_][3] = d_.w; \
        }                                                                     \
        _Pragma("unroll")                                                     \
        for (int j_ = 0; j_ < 4; ++j_) {                                      \
          float4 s_ = *(const float4*)(&sP[q0_ + j_][C4]);                    \
          sv[j_][0] = s_.x; sv[j_][1] = s_.y; sv[j_][2] = s_.z; sv[j_][3] = s_.w; \
        }                                                                     \
      } while (0)
    #define LOADCH_MC(dv, sv, ch)                                             \
      do {                                                                    \
        const int q0_ = (ch) * 4;                                             \
        _Pragma("unroll")                                                     \
        for (int r_ = 0; r_ < 4; ++r_) {                                      \
          float4 d_ = *(const float4*)(&sMC[R4 + r_][q0_]);                   \
          dv[r_][0] = d_.x; dv[r_][1] = d_.y; dv[r_][2] = d_.z; dv[r_][3] = d_.w; \
        }                                                                     \
        _Pragma("unroll")                                                     \
        for (int j_ = 0; j_ < 4; ++j_) {                                      \
          float4 s_ = *(const float4*)(&sP[q0_ + j_][C4]);                    \
          sv[j_][0] = s_.x; sv[j_][1] = s_.y; sv[j_][2] = s_.z; sv[j_][3] = s_.w; \
        }                                                                     \
      } while (0)
    #define FMACH(acc, dv, sv, sgn)                                           \
      do {                                                                    \
        _Pragma("unroll")                                                     \
        for (int j_ = 0; j_ < 4; ++j_)                                        \
          _Pragma("unroll")                                                   \
          for (int r_ = 0; r_ < 4; ++r_)                                      \
            _Pragma("unroll")                                                 \
            for (int c_ = 0; c_ < 4; ++c_)                                    \
              acc[r_][c_] = fmaf(sgn dv[r_][j_], sv[j_][c_], acc[r_][c_]);    \
      } while (0)

    float pb[4][4] = {{0.f}};
    {
      float dvA[4][4], svA[4][4], dvB[4][4], svB[4][4];
      LOADCH_PB(dvA, svA, 0);
      #pragma unroll
      for (int ch = 0; ch < 16; ch += 2) {
        LOADCH_PB(dvB, svB, ch + 1);
        FMACH(pb, dvA, svA, +);
        if (ch + 2 < 16) LOADCH_PB(dvA, svA, ch + 2);
        FMACH(pb, dvB, svB, +);
      }
    }
    __syncthreads();
    #pragma unroll
    for (int r = 0; r < 4; ++r)
      *(float4*)(&sP[R4 + r][C4]) = make_float4(pb[r][0], pb[r][1], pb[r][2], pb[r][3]);
    __syncthreads();

    float o[4][4];
    if (blockIdx.x == (unsigned)s) {
      #pragma unroll
      for (int r = 0; r < 4; ++r)
        #pragma unroll
        for (int c = 0; c < 4; ++c) o[r][c] = pb[r][c];
    } else {
      #pragma unroll
      for (int r = 0; r < 4; ++r)
        #pragma unroll
        for (int c = 0; c < 4; ++c) o[r][c] = av4[r][c];
      float dvA[4][4], svA[4][4], dvB[4][4], svB[4][4];
      LOADCH_MC(dvA, svA, 0);
      #pragma unroll
      for (int ch = 0; ch < 16; ch += 2) {
        LOADCH_MC(dvB, svB, ch + 1);
        FMACH(o, dvA, svA, -);
        if (ch + 2 < 16) LOADCH_MC(dvA, svA, ch + 2);
        FMACH(o, dvB, svB, -);
      }
    }
    #undef LOADCH_PB
    #undef LOADCH_MC
    #undef FMACH
    if (last) {                       // G rows of Wfull (c0 >= 512 at s=7)
      int k0 = c0 - 512 + C4;
      #pragma unroll
      for (int r = 0; r < 4; ++r) {
        ushort4 h = { f2bf(o[r][0]), f2bf(o[r][1]), f2bf(o[r][2]), f2bf(o[r][3]) };
        *(ushort4*)(Wfull + (size_t)(r0 + R4 + r) * KP + k0) = h;
      }
    } else {
      #pragma unroll
      for (int r = 0; r < 4; ++r)
        *(float4*)(Aout + (size_t)(r0 + R4 + r) * AUGW + c0 + C4) =
            make_float4(o[r][0], o[r][1], o[r][2], o[r][3]);
    }
    return;
  }

  // =================== extra blocks: independent-chain slices ===================
  const int g = ebase + ((int)blockIdx.y - nby) * 8 + (int)blockIdx.x;

  if (g < 256) {
    // ---- gemm-xu slice: xu[m][n] = sum_k P[m][k] * Wxu[n][k] (n < 256) ----
    ushort* sA = (ushort*)smem;            // 3 * 4096 ushorts
    ushort* sB = (ushort*)(smem + 24576);
    const int mb = g >> 1, nb = g & 1;
    int wm = wave & 1, wn = wave >> 1;
    int m0 = mb * 128, n0 = nb * 128;
    int r16 = lane & 15, kq = lane >> 4;
    int lrow = lane >> 2, lseg = lane & 3;
    const ushort* gA0 = P + (size_t)(m0 + wave * 32 + lrow) * KP + lseg * 8;
    const ushort* gA1 = gA0 + 16 * KP;
    const ushort* gB0 = Wxu + (size_t)(n0 + wave * 32 + lrow) * KP + lseg * 8;
    const ushort* gB1 = gB0 + 16 * KP;

    #define STAGE_KB(bi, kb_)                                              \
      do {                                                                 \
        GLOAD_LDS16(gA0 + (kb_) * 32, sA + (bi) * 4096 + wave * 1024);     \
        GLOAD_LDS16(gA1 + (kb_) * 32, sA + (bi) * 4096 + wave * 1024 + 512); \
        GLOAD_LDS16(gB0 + (kb_) * 32, sB + (bi) * 4096 + wave * 1024);     \
        GLOAD_LDS16(gB1 + (kb_) * 32, sB + (bi) * 4096 + wave * 1024 + 512); \
      } while (0)

    f32x4 acc[4][4] = {};
    const int NKB = KP / 32;   // 32
    STAGE_KB(0, 0);
    STAGE_KB(1, 1);
    #pragma unroll
    for (int kb = 0; kb < NKB; ++kb) {
      const int bi = kb % 3;
      if (kb + 2 < NKB) {
        STAGE_KB((kb + 2) % 3, kb + 2);
        asm volatile("s_waitcnt vmcnt(8)" ::: "memory");
      } else if (kb + 2 == NKB) {
        asm volatile("s_waitcnt vmcnt(4)" ::: "memory");
      } else {
        asm volatile("s_waitcnt vmcnt(0)" ::: "memory");
      }
      __builtin_amdgcn_s_barrier();
      __builtin_amdgcn_sched_barrier(0);
      short8 af[4], bf[4];
      #pragma unroll
      for (int t = 0; t < 4; ++t) {
        af[t] = *(const short8*)(sA + bi * 4096 + (wm * 64 + t * 16 + r16) * 32 + kq * 8);
        bf[t] = *(const short8*)(sB + bi * 4096 + (wn * 64 + t * 16 + r16) * 32 + kq * 8);
      }
      #pragma unroll
      for (int mt = 0; mt < 4; ++mt)
        #pragma unroll
        for (int nt = 0; nt < 4; ++nt)
          acc[mt][nt] = __builtin_amdgcn_mfma_f32_16x16x32_bf16(af[mt], bf[nt], acc[mt][nt], 0, 0, 0);
      __builtin_amdgcn_sched_barrier(0);
      __builtin_amdgcn_s_barrier();
    }
    #undef STAGE_KB

    #pragma unroll
    for (int mt = 0; mt < 4; ++mt)
      #pragma unroll
      for (int nt = 0; nt < 4; ++nt)
        #pragma unroll
        for (int i = 0; i < 4; ++i) {
          int m = m0 + wm * 64 + mt * 16 + kq * 4 + i;
          int n = n0 + wn * 64 + nt * 16 + r16;
          xu[(size_t)m * NQq + n] = acc[mt][nt][i];
        }
    return;
  }

  if (g >= 336 && g < 592) {
    // ---- solve slice (runs in launches 4-6; xu complete by end of launch 3) ----
    const int sid = g - 336;
    ushort* wB = (ushort*)smem;                               // 4*16*WSTRIDE ushorts
    float (*d11T)[16][16] = (float (*)[16][16])(smem + 33792);
    const int r0w = sid * 64 + wave * 16;
    const int bp4 = (((lane >> 2) | ((lane & 3) << 4)) << 2); // bpermute byte addr
    for (int i = tid; i < 4096; i += 256) {
      int tt = i >> 8, j = (i >> 4) & 15, c = i & 15;
      d11T[tt][j][c] = (c > j) ? D11[(size_t)(tt * 16 + c) * NQq + tt * 16 + j] : 0.f;
    }
    Pre pre0, pre1;
    tile_loads<0>(xu, D11B, lam, bv, lane, r0w, pre0);
    __syncthreads();                          // the only block-wide barrier
    ushort* wb = wB + wave * 16 * WSTRIDE;
    short8 whiF[8] = {};
    do_tile<0>(xu, D11B, lam, bv, wb, d11T, whiF, lane, bp4, r0w, pre0, pre1);
    do_tile<1>(xu, D11B, lam, bv, wb, d11T, whiF, lane, bp4, r0w, pre1, pre0);
    do_tile<2>(xu, D11B, lam, bv, wb, d11T, whiF, lane, bp4, r0w, pre0, pre1);
    do_tile<3>(xu, D11B, lam, bv, wb, d11T, whiF, lane, bp4, r0w, pre1, pre0);
    do_tile<4>(xu, D11B, lam, bv, wb, d11T, whiF, lane, bp4, r0w, pre0, pre1);
    do_tile<5>(xu, D11B, lam, bv, wb, d11T, whiF, lane, bp4, r0w, pre1, pre0);
    do_tile<6>(xu, D11B, lam, bv, wb, d11T, whiF, lane, bp4, r0w, pre0, pre1);
    do_tile<7>(xu, D11B, lam, bv, wb, d11T, whiF, lane, bp4, r0w, pre1, pre0);
    do_tile<8>(xu, D11B, lam, bv, wb, d11T, whiF, lane, bp4, r0w, pre0, pre1);
    do_tile<9>(xu, D11B, lam, bv, wb, d11T, whiF, lane, bp4, r0w, pre1, pre0);
    do_tile<10>(xu, D11B, lam, bv, wb, d11T, whiF, lane, bp4, r0w, pre0, pre1);
    do_tile<11>(xu, D11B, lam, bv, wb, d11T, whiF, lane, bp4, r0w, pre1, pre0);
    do_tile<12>(xu, D11B, lam, bv, wb, d11T, whiF, lane, bp4, r0w, pre0, pre1);
    do_tile<13>(xu, D11B, lam, bv, wb, d11T, whiF, lane, bp4, r0w, pre1, pre0);
    do_tile<14>(xu, D11B, lam, bv, wb, d11T, whiF, lane, bp4, r0w, pre0, pre1);
    do_tile<15>(xu, D11B, lam, bv, wb, d11T, whiF, lane, bp4, r0w, pre1, pre0);
    #pragma unroll
    for (int it = 0; it < 8; ++it) {
      int f = it * 64 + lane;
      int m = f >> 5, k8 = f & 31;
      uint4 v = *(const uint4*)(wb + m * WSTRIDE + k8 * 8);
      *(uint4*)(P + (size_t)(r0w + m) * KP + NXq + k8 * 8) = v;
    }
    return;
  }
  // remaining extras: idle
}

// ---------------- bf16 MFMA GEMM (final dx,y): out[m][n] = sum_k P[m][k] * W[n][k] ----------------
__global__ __launch_bounds__(256) void k_gemm(const ushort* __restrict__ P, const ushort* __restrict__ W,
                                              float* __restrict__ out) {
  __shared__ ushort sA[3][128 * 32];
  __shared__ ushort sB[3][128 * 32];
  int tid = threadIdx.x;
  int lane = tid & 63, wave = tid >> 6;
  int wm = wave & 1, wn = wave >> 1;
  int m0 = blockIdx.x * 128;
  int n0 = blockIdx.y * 128;
  int r16 = lane & 15, kq = lane >> 4;
  int lrow = lane >> 2, lseg = lane & 3;
  const ushort* gA0 = P + (size_t)(m0 + wave * 32 + lrow) * KP + lseg * 8;
  const ushort* gA1 = gA0 + 16 * KP;
  const ushort* gB0 = W + (size_t)(n0 + wave * 32 + lrow) * KP + lseg * 8;
  const ushort* gB1 = gB0 + 16 * KP;

  #define STAGE_KB(bi, kb_)                                        \
    do {                                                           \
      GLOAD_LDS16(gA0 + (kb_) * 32, &sA[bi][wave * 1024]);         \
      GLOAD_LDS16(gA1 + (kb_) * 32, &sA[bi][wave * 1024 + 512]);   \
      GLOAD_LDS16(gB0 + (kb_) * 32, &sB[bi][wave * 1024]);         \
      GLOAD_LDS16(gB1 + (kb_) * 32, &sB[bi][wave * 1024 + 512]);   \
    } while (0)

  f32x4 acc[4][4] = {};
  const int NKB = KP / 32;   // 32
  STAGE_KB(0, 0);
  STAGE_KB(1, 1);
  #pragma unroll
  for (int kb = 0; kb < NKB; ++kb) {
    const int bi = kb % 3;
    if (kb + 2 < NKB) {
      STAGE_KB((kb + 2) % 3, kb + 2);
      asm volatile("s_waitcnt vmcnt(8)" ::: "memory");   // stage kb (own 4 loads) done
    } else if (kb + 2 == NKB) {
      asm volatile("s_waitcnt vmcnt(4)" ::: "memory");
    } else {
      asm volatile("s_waitcnt vmcnt(0)" ::: "memory");
    }
    __builtin_amdgcn_s_barrier();          // all waves' stage kb complete
    __builtin_amdgcn_sched_barrier(0);     // pin: no ds_read hoists above barrier
    short8 af[4], bf[4];
    #pragma unroll
    for (int t = 0; t < 4; ++t) {
      af[t] = *(const short8*)(&sA[bi][(wm * 64 + t * 16 + r16) * 32 + kq * 8]);
      bf[t] = *(const short8*)(&sB[bi][(wn * 64 + t * 16 + r16) * 32 + kq * 8]);
    }
    #pragma unroll
    for (int mt = 0; mt < 4; ++mt)
      #pragma unroll
      for (int nt = 0; nt < 4; ++nt)
        acc[mt][nt] = __builtin_amdgcn_mfma_f32_16x16x32_bf16(af[mt], bf[nt], acc[mt][nt], 0, 0, 0);
    __builtin_amdgcn_sched_barrier(0);     // pin: reads complete before end barrier
    __builtin_amdgcn_s_barrier();          // reads of buf bi done before overwrite
  }
  #undef STAGE_KB

  #pragma unroll
  for (int mt = 0; mt < 4; ++mt)
    #pragma unroll
    for (int nt = 0; nt < 4; ++nt)
      #pragma unroll
      for (int i = 0; i < 4; ++i) {
        int m = m0 + wm * 64 + mt * 16 + kq * 4 + i;
        int n = n0 + wn * 64 + nt * 16 + r16;
        float val = acc[mt][nt][i];
        if (n < NXq) out[(size_t)m * NXq + n] = val;
        else out[(size_t)NBq * NXq + (size_t)m * NYq + (n - NXq)] = val;
      }
}

extern "C" void kernel_launch(void* const* d_in, const int* in_sizes, int n_in,
                              void* d_out, int out_size, void* d_ws, size_t ws_size,
                              hipStream_t stream) {
  const float* x   = (const float*)d_in[0];
  const float* u   = (const float*)d_in[1];
  const float* F   = (const float*)d_in[2];
  const float* B1  = (const float*)d_in[3];
  const float* B2  = (const float*)d_in[4];
  const float* C1  = (const float*)d_in[5];
  const float* C2  = (const float*)d_in[6];
  const float* D11 = (const float*)d_in[7];
  const float* D12 = (const float*)d_in[8];
  const float* D21 = (const float*)d_in[9];
  const float* E   = (const float*)d_in[10];
  const float* lam = (const float*)d_in[11];
  const float* bv  = (const float*)d_in[12];

  char* ws = (char*)d_ws;
  ushort* P    = (ushort*)ws;                                     // 32 MB
  float* xu    = (float*)(ws + (size_t)(32u << 20));              // 16 MB
  float* AUG0  = (float*)(ws + (size_t)(48u << 20));              // 3 MB
  float* AUG1  = (float*)(ws + (size_t)(52u << 20));              // 3 MB
  ushort* Wfull = (ushort*)(ws + (size_t)(56u << 20));            // 1.25 MB bf16
  ushort* Wxu   = (ushort*)(ws + (size_t)(58u << 20));            // 0.5 MB bf16
  ushort* D11B  = (ushort*)(ws + (size_t)(59u << 20));            // 128 KB bf16
  float* out   = (float*)d_out;
  float* AUGbuf[2] = { AUG0, AUG1 };

  // extra-slot bases: cumulative idle-block counts before each GJ launch
  static const int ebase_tab[8] = {0, 72, 152, 240, 336, 440, 552, 672};

  k_prep<<<17152, 256, 0, stream>>>(x, u, E, F, B1, B2, C1, C2, D11, D12, D21,
                                    P, AUG0, Wxu, D11B, Wfull);
  for (int s = 0; s < 8; ++s)
    k_fused<<<dim3(8, 32), 256, 0, stream>>>(AUGbuf[s & 1], AUGbuf[(s + 1) & 1],
                                             Wfull, s, ebase_tab[s],
                                             P, Wxu, xu, D11, D11B, lam, bv);
  k_gemm<<<dim3(128, 5), 256, 0, stream>>>(P, Wfull, out);        // dx, y
}